// Round 2
// baseline (181.496 us; speedup 1.0000x reference)
//
#include <hip/hip_runtime.h>

#define NJ  24
#define BPB 64     // batch elements per block
#define TPB 256    // threads per block
#define RST 217    // per-batch LDS stride in floats (216 + 1 pad, odd -> conflict-free)
#define OST 73     // output staging stride (72 + 1 pad)

__global__ __launch_bounds__(TPB) void smpl_fk_kernel(
    const float* __restrict__ orient,   // [B,24,3,3]
    const float* __restrict__ offs,     // [24,3]
    float* __restrict__ out)            // [B,24,3]
{
    // parent of each joint (joint 0 is root)
    constexpr int PAR[NJ] = {-1, 0, 1, 2, 3, 0, 5, 6, 7, 0, 9, 10, 11,
                             12, 11, 14, 15, 16, 17, 11, 19, 20, 21, 22};

    __shared__ float lds[BPB * RST];   // 55,552 B: input staging, reused for output staging
    __shared__ float soff[NJ * 3];

    const int tid = threadIdx.x;
    const long long b0 = (long long)blockIdx.x * BPB;

    // ---- stage offsets (72 floats) ----
    if (tid < NJ * 3) soff[tid] = offs[tid];

    // ---- stage rotations: 64 batches * 216 floats = 3456 float4, coalesced ----
    const float4* gin = (const float4*)(orient + b0 * (NJ * 9));
    #pragma unroll
    for (int i = 0; i < 14; ++i) {
        int f4 = i * TPB + tid;
        if (f4 < BPB * 54) {
            float4 v = gin[f4];
            int b = f4 / 54;            // batch within block
            int w = f4 % 54;            // float4 index within batch
            float* dst = &lds[b * RST + w * 4];
            dst[0] = v.x; dst[1] = v.y; dst[2] = v.z; dst[3] = v.w;
        }
    }
    __syncthreads();

    // ---- per-batch tree walk: one thread per batch element (wave 0) ----
    // final[b,i,m] = sum_{j in anc(i), j!=0} sum_l R[b, par(j), m, l] * offs[j, d(l)],  d=[1,2,0]
    float pos[NJ][3];
    if (tid < BPB) {
        const float* Rb = &lds[tid * RST];
        pos[0][0] = 0.f; pos[0][1] = 0.f; pos[0][2] = 0.f;
        #pragma unroll
        for (int j = 1; j < NJ; ++j) {
            const int p = PAR[j];
            const float o0 = soff[j * 3 + 1];   // offsets[j][d(0)] = offsets[j][1]
            const float o1 = soff[j * 3 + 2];   // offsets[j][d(1)] = offsets[j][2]
            const float o2 = soff[j * 3 + 0];   // offsets[j][d(2)] = offsets[j][0]
            #pragma unroll
            for (int m = 0; m < 3; ++m) {
                const float r0 = Rb[p * 9 + m * 3 + 0];
                const float r1 = Rb[p * 9 + m * 3 + 1];
                const float r2 = Rb[p * 9 + m * 3 + 2];
                pos[j][m] = fmaf(r0, o0, fmaf(r1, o1, fmaf(r2, o2, pos[p][m])));
            }
        }
    }
    __syncthreads();   // all compute-phase LDS reads done before we overwrite for output staging

    if (tid < BPB) {
        float* ob = &lds[tid * OST];
        #pragma unroll
        for (int j = 0; j < NJ; ++j) {
            ob[j * 3 + 0] = pos[j][0];
            ob[j * 3 + 1] = pos[j][1];
            ob[j * 3 + 2] = pos[j][2];
        }
    }
    __syncthreads();

    // ---- coalesced write-out: 64 batches * 72 floats = 4608 = 18 * 256 ----
    float* gout = out + b0 * (NJ * 3);
    #pragma unroll
    for (int i = 0; i < 18; ++i) {
        int idx = i * TPB + tid;
        int b = idx / 72;
        int w = idx % 72;
        gout[idx] = lds[b * OST + w];
    }
}

extern "C" void kernel_launch(void* const* d_in, const int* in_sizes, int n_in,
                              void* d_out, int out_size, void* d_ws, size_t ws_size,
                              hipStream_t stream) {
    const float* orient = (const float*)d_in[0];
    const float* offs   = (const float*)d_in[1];
    float* out          = (float*)d_out;

    const int B = in_sizes[0] / (NJ * 9);      // 131072
    const int blocks = (B + BPB - 1) / BPB;    // 2048
    smpl_fk_kernel<<<blocks, TPB, 0, stream>>>(orient, offs, out);
}

// Round 3
// 179.746 us; speedup vs baseline: 1.0097x; 1.0097x over previous
//
#include <hip/hip_runtime.h>

#define NJ  24
#define BPB 32     // batch elements per block (131072 % 32 == 0)
#define TPB 256    // threads per block
#define RST 217    // per-batch LDS stride in floats (216 + 1, odd -> coprime with 32 banks)
#define OST 73     // output staging stride (72 + 1)

__global__ __launch_bounds__(TPB) void smpl_fk_kernel(
    const float* __restrict__ orient,   // [B,24,3,3]
    const float* __restrict__ offs,     // [24,3]
    float* __restrict__ out)            // [B,24,3]
{
    // parent of each joint (joint 0 is root)
    constexpr int PAR[NJ] = {-1, 0, 1, 2, 3, 0, 5, 6, 7, 0, 9, 10, 11,
                             12, 11, 14, 15, 16, 17, 11, 19, 20, 21, 22};

    __shared__ float lds[BPB * RST];   // 27,776 B input staging, reused for output staging
    __shared__ float soff[NJ * 3];

    const int tid = threadIdx.x;
    const long long b0 = (long long)blockIdx.x * BPB;

    // ---- stage offsets (72 floats, broadcast-read later) ----
    if (tid < NJ * 3) soff[tid] = offs[tid];

    // ---- stage rotations: 32 batches * 54 float4 = 1728 float4, coalesced ----
    const float4* gin = (const float4*)(orient + b0 * (NJ * 9));
    #pragma unroll
    for (int i = 0; i < 7; ++i) {
        int f4 = i * TPB + tid;
        if (f4 < BPB * 54) {
            float4 v = gin[f4];
            int b = f4 / 54;            // batch within block
            int w = f4 % 54;            // float4 index within batch
            float* dst = &lds[b * RST + w * 4];
            dst[0] = v.x; dst[1] = v.y; dst[2] = v.z; dst[3] = v.w;
        }
    }
    __syncthreads();

    // ---- tree walk: 3 threads per batch (one per output component m) ----
    // final[b,i,m] = sum_{j in anc(i), j!=0} R[b, par(j), m, :] . (off[j,1], off[j,2], off[j,0])
    float pos[NJ];
    if (tid < BPB * 3) {
        const int b = tid & (BPB - 1);
        const int m = tid >> 5;                  // 0,1,2
        const float* Rb = &lds[b * RST + m * 3]; // row m of each 3x3
        pos[0] = 0.f;
        #pragma unroll
        for (int j = 1; j < NJ; ++j) {
            const int p = PAR[j];
            pos[j] = fmaf(Rb[p * 9 + 0], soff[j * 3 + 1],
                     fmaf(Rb[p * 9 + 1], soff[j * 3 + 2],
                     fmaf(Rb[p * 9 + 2], soff[j * 3 + 0], pos[p])));
        }
    }
    __syncthreads();   // compute-phase LDS reads done before overwrite

    if (tid < BPB * 3) {
        const int b = tid & (BPB - 1);
        const int m = tid >> 5;
        float* ob = &lds[b * OST + m];
        #pragma unroll
        for (int j = 0; j < NJ; ++j) ob[j * 3] = pos[j];
    }
    __syncthreads();

    // ---- coalesced write-out: 32 batches * 72 floats = 2304 = 9 * 256 ----
    float* gout = out + b0 * (NJ * 3);
    #pragma unroll
    for (int i = 0; i < 9; ++i) {
        int idx = i * TPB + tid;
        int b = idx / 72;
        int w = idx % 72;
        gout[idx] = lds[b * OST + w];
    }
}

extern "C" void kernel_launch(void* const* d_in, const int* in_sizes, int n_in,
                              void* d_out, int out_size, void* d_ws, size_t ws_size,
                              hipStream_t stream) {
    const float* orient = (const float*)d_in[0];
    const float* offs   = (const float*)d_in[1];
    float* out          = (float*)d_out;

    const int B = in_sizes[0] / (NJ * 9);      // 131072
    const int blocks = (B + BPB - 1) / BPB;    // 4096
    smpl_fk_kernel<<<blocks, TPB, 0, stream>>>(orient, offs, out);
}